// Round 3
// baseline (415.248 us; speedup 1.0000x reference)
//
#include <hip/hip_runtime.h>
#include <stdint.h>
#include <math.h>

using f32x4  = __attribute__((ext_vector_type(4)))  float;
using f32x16 = __attribute__((ext_vector_type(16))) float;
using s16x8  = __attribute__((ext_vector_type(8)))  short;

#define DI __device__ __forceinline__

DI unsigned short f2bf(float f) {
  unsigned u = __float_as_uint(f);
  u += 0x7FFFu + ((u >> 16) & 1u);
  return (unsigned short)(u >> 16);
}
DI float bf2f(unsigned short h) { return __uint_as_float((unsigned)h << 16); }

// ---------------------------------------------------------------- f32 -> bf16
__global__ void k_cvt_bf16(const float* __restrict__ in, unsigned short* __restrict__ out, int n4) {
  int i = blockIdx.x * blockDim.x + threadIdx.x;
  const int stride = gridDim.x * blockDim.x;
  for (; i < n4; i += stride) {
    float4 v = reinterpret_cast<const float4*>(in)[i];
    ushort4 o;
    o.x = f2bf(v.x); o.y = f2bf(v.y); o.z = f2bf(v.z); o.w = f2bf(v.w);
    reinterpret_cast<ushort4*>(out)[i] = o;
  }
}

// ---------------------------------------------------------------- rope tables (2048 x 32)
__global__ void k_rope_table(float* __restrict__ cost, float* __restrict__ sint) {
  const int idx = blockIdx.x * 256 + threadIdx.x;  // 65536
  const int s = idx >> 5, fi = idx & 31;
  const double invf = pow(10000.0, -(double)fi / 32.0);
  const float ang = (float)s * (float)invf;
  cost[idx] = (float)cos((double)ang);
  sint[idx] = (float)sin((double)ang);
}

// ---------------------------------------------------------------- bf16 GEMM  C[M][N] = A[M][K]*B[N][K]^T + bias
__global__ __launch_bounds__(256) void k_gemm_bt(
    const unsigned short* __restrict__ A, const unsigned short* __restrict__ B,
    const float* __restrict__ bias, float* __restrict__ C, int M, int N, int K) {
  __shared__ unsigned short As[128 * 32], Bs[128 * 32];
  const int tid = threadIdx.x, l = tid & 63, w = tid >> 6;
  const int wr = w >> 1, wc = w & 1;
  const int m0 = blockIdx.x * 128, n0 = blockIdx.y * 128;
  const int srow = tid >> 2, scol = (tid & 3) * 8;
  f32x4 acc[4][4] = {};
  for (int k0 = 0; k0 < K; k0 += 32) {
    s16x8 a0 = *(const s16x8*)(A + (size_t)(m0 + srow) * K + k0 + scol);
    s16x8 a1 = *(const s16x8*)(A + (size_t)(m0 + 64 + srow) * K + k0 + scol);
    s16x8 b0 = *(const s16x8*)(B + (size_t)(n0 + srow) * K + k0 + scol);
    s16x8 b1 = *(const s16x8*)(B + (size_t)(n0 + 64 + srow) * K + k0 + scol);
    __syncthreads();
    *(s16x8*)&As[srow * 32 + scol] = a0;
    *(s16x8*)&As[(64 + srow) * 32 + scol] = a1;
    *(s16x8*)&Bs[srow * 32 + scol] = b0;
    *(s16x8*)&Bs[(64 + srow) * 32 + scol] = b1;
    __syncthreads();
    s16x8 af[4], bf[4];
#pragma unroll
    for (int i = 0; i < 4; i++)
      af[i] = *(const s16x8*)&As[(wr * 64 + i * 16 + (l & 15)) * 32 + (l >> 4) * 8];
#pragma unroll
    for (int j = 0; j < 4; j++)
      bf[j] = *(const s16x8*)&Bs[(wc * 64 + j * 16 + (l & 15)) * 32 + (l >> 4) * 8];
#pragma unroll
    for (int i = 0; i < 4; i++)
#pragma unroll
      for (int j = 0; j < 4; j++)
        acc[i][j] = __builtin_amdgcn_mfma_f32_16x16x32_bf16(af[i], bf[j], acc[i][j], 0, 0, 0);
  }
#pragma unroll
  for (int i = 0; i < 4; i++) {
    const int row = m0 + wr * 64 + i * 16 + (l >> 4) * 4;
#pragma unroll
    for (int j = 0; j < 4; j++) {
      const int col = n0 + wc * 64 + j * 16 + (l & 15);
      const float bv = bias ? bias[col] : 0.f;
#pragma unroll
      for (int r = 0; r < 4; r++) C[(size_t)(row + r) * N + col] = acc[i][j][r] + bv;
    }
  }
}

// ---------------------------------------------------------------- RoPE + relayout
// rotate_half pairs heads h^8 (sign - for h<8); tables indexed by (s, d&31).
__global__ void k_rope_relayout(const float* __restrict__ qkv, const float* __restrict__ cost,
                                const float* __restrict__ sint,
                                unsigned short* __restrict__ qh, unsigned short* __restrict__ kh,
                                unsigned short* __restrict__ vt) {
  const int s = blockIdx.x, t = threadIdx.x;
  const float* row = qkv + (size_t)s * 3072;
  const int c = t * 4;
  const int d = c >> 4;
  const int hbase = c & 15;
  const float cv = cost[s * 32 + (d & 31)];
  const float sv = sint[s * 32 + (d & 31)];
  const float sgn = (hbase < 8) ? -1.f : 1.f;
  {
    float4 v = *(const float4*)(row + c);
    float4 v2 = *(const float4*)(row + (c ^ 8));
    const float* vp = (const float*)&v;
    const float* vp2 = (const float*)&v2;
#pragma unroll
    for (int i = 0; i < 4; i++) {
      float val = vp[i] * cv + sgn * vp2[i] * sv;
      qh[(size_t)(hbase + i) * (2048 * 64) + s * 64 + d] = f2bf(val);
    }
  }
  {
    float4 v = *(const float4*)(row + 1024 + c);
    float4 v2 = *(const float4*)(row + 1024 + (c ^ 8));
    const float* vp = (const float*)&v;
    const float* vp2 = (const float*)&v2;
#pragma unroll
    for (int i = 0; i < 4; i++) {
      float val = vp[i] * cv + sgn * vp2[i] * sv;
      kh[(size_t)(hbase + i) * (2048 * 64) + s * 64 + d] = f2bf(val);
    }
  }
  {
    float4 v = *(const float4*)(row + 2048 + c);
    const float* vp = (const float*)&v;
#pragma unroll
    for (int i = 0; i < 4; i++)
      vt[(size_t)(hbase + i) * (64 * 2048) + (size_t)d * 2048 + s] = f2bf(vp[i]);
  }
}

// ---------------------------------------------------------------- bias+mask pre-pass
// in : bias fp32 [j][k][h16], mask int32 same
// out: bmG bf16 [h][ko=k/4][j][ki=k%4]  (so attn reads 8B/lane in S^T reg order)
#define PH 1092  // LDS h-plane stride in shorts (j stride 34)
__global__ __launch_bounds__(256) void k_prep(const float* __restrict__ bias,
                                              const int* __restrict__ mask,
                                              unsigned short* __restrict__ bmG) {
  __shared__ unsigned short lds[16 * PH];
  const int t = threadIdx.x;
  const int j0 = blockIdx.x * 32, k0 = blockIdx.y * 32;
  const int j_r = t >> 3;
  const size_t rowbase = ((size_t)(j0 + j_r) * 2048 + k0) * 16;
  const float* bro = bias + rowbase;
  const int* mro = mask + rowbase;
#pragma unroll
  for (int i = 0; i < 16; ++i) {
    const int f = (t & 7) + 8 * i;
    float4 bv = *(const float4*)(bro + f * 4);
    int4 mv = *(const int4*)(mro + f * 4);
    const int k_l = f >> 2, h0 = 4 * (f & 3);
    const float* bvp = (const float*)&bv;
    const int* mvp = (const int*)&mv;
#pragma unroll
    for (int e = 0; e < 4; ++e)
      lds[(h0 + e) * PH + j_r * 34 + k_l] = f2bf(mvp[e] ? bvp[e] : -1.0e8f);
  }
  __syncthreads();
  const int rc = t >> 1, half = t & 1;
  const int hh = rc >> 3, ko_l = rc & 7;
  unsigned short* outp = bmG + (((size_t)hh * 512 + (size_t)(k0 >> 2) + ko_l) * 2048 + j0 + half * 16) * 4;
  const unsigned short* lp = &lds[hh * PH + (half * 16) * 34 + 4 * ko_l];
#pragma unroll
  for (int s = 0; s < 8; ++s) {
    uint2 a = *(const uint2*)(lp + (2 * s) * 34);
    uint2 b = *(const uint2*)(lp + (2 * s + 1) * 34);
    uint4 o; o.x = a.x; o.y = a.y; o.z = b.x; o.w = b.y;
    *(uint4*)(outp + (2 * s) * 4) = o;
  }
}

// ---------------------------------------------------------------- attention (barrier-free)
// grid (q4=4, jt=64, ks=4), 256 threads = 4 waves, 1 head/wave, 32 q-rows, 512 k per block
__global__ __launch_bounds__(256, 3) void k_attn(
    const unsigned short* __restrict__ bmG,
    const unsigned short* __restrict__ qh, const unsigned short* __restrict__ kh,
    const unsigned short* __restrict__ vt,
    float* __restrict__ Opart, float* __restrict__ ML) {
  const int tid = threadIdx.x, l = tid & 63, w = tid >> 6;
  const int hi = l >> 5, ln = l & 31;
  const int q4 = blockIdx.x, jt = blockIdx.y, ks = blockIdx.z;
  const int j0 = jt * 32, h = q4 * 4 + w, kstart = ks * 512;

  s16x8 qf[4];
  {
    const unsigned short* qb = qh + ((size_t)h * 2048 + (j0 + ln)) * 64 + 8 * hi;
#pragma unroll
    for (int ds = 0; ds < 4; ds++) qf[ds] = *(const s16x8*)(qb + ds * 16);
  }
  const unsigned short* kb = kh + ((size_t)h * 2048 + (kstart + ln)) * 64 + 8 * hi;
  const unsigned short* vb = vt + (size_t)h * 64 * 2048 + (size_t)ln * 2048 + kstart + 8 * hi;
  const uint2* bp = (const uint2*)bmG + ((size_t)h * 512 + (size_t)ks * 128 + hi) * 2048 + j0 + ln;
  // chunk c at iter it lives at bp + (it*8 + 2c)*2048

  f32x16 o0 = {}, o1 = {};
  float mrun = -3.0e38f, lrun = 0.f;

  uint2 bnx[4];
#pragma unroll
  for (int c = 0; c < 4; c++) bnx[c] = bp[(size_t)(2 * c) * 2048];

  for (int it = 0; it < 16; ++it) {
    uint2 bcur[4];
#pragma unroll
    for (int c = 0; c < 4; c++) bcur[c] = bnx[c];
    if (it + 1 < 16) {
#pragma unroll
      for (int c = 0; c < 4; c++) bnx[c] = bp[(size_t)((it + 1) * 8 + 2 * c) * 2048];
    }
    s16x8 kf[4], vf[4];
    {
      const unsigned short* kp = kb + (size_t)it * (32 * 64);
#pragma unroll
      for (int ds = 0; ds < 4; ds++) kf[ds] = *(const s16x8*)(kp + ds * 16);
      const unsigned short* vp = vb + (size_t)it * 32;
      vf[0] = *(const s16x8*)(vp);
      vf[1] = *(const s16x8*)(vp + 32 * 2048);
      vf[2] = *(const s16x8*)(vp + 16);
      vf[3] = *(const s16x8*)(vp + 32 * 2048 + 16);
    }
    // S^T = K*Q^T : reg r -> kl=(r&3)+8*(r>>2)+4*hi, lane ln -> j
    f32x16 st = {};
#pragma unroll
    for (int ds = 0; ds < 4; ds++)
      st = __builtin_amdgcn_mfma_f32_32x32x16_bf16(kf[ds], qf[ds], st, 0, 0, 0);
    float p[16];
    float tmax = -3.0e38f;
#pragma unroll
    for (int r = 0; r < 16; r++) {
      const unsigned word = (r & 2) ? bcur[r >> 2].y : bcur[r >> 2].x;
      const unsigned short u = (r & 1) ? (unsigned short)(word >> 16) : (unsigned short)(word & 0xffffu);
      const float sv = st[r] * 0.125f + bf2f(u);
      p[r] = sv;
      tmax = fmaxf(tmax, sv);
    }
    tmax = fmaxf(tmax, __shfl_xor(tmax, 32));
    const float mnew = fmaxf(mrun, tmax);
    const float sc = __expf(mrun - mnew);
    float psum = 0.f;
#pragma unroll
    for (int r = 0; r < 16; r++) { p[r] = __expf(p[r] - mnew); psum += p[r]; }
    psum += __shfl_xor(psum, 32);
    lrun = lrun * sc + psum;
    mrun = mnew;
#pragma unroll
    for (int r = 0; r < 16; r++) {
      const int jj = (r & 3) + 8 * (r >> 2) + 4 * hi;
      const float s2 = __shfl(sc, jj);
      o0[r] *= s2;
      o1[r] *= s2;
    }
    unsigned pk[8];
#pragma unroll
    for (int q = 0; q < 8; q++)
      pk[q] = (unsigned)f2bf(p[2 * q]) | ((unsigned)f2bf(p[2 * q + 1]) << 16);
#pragma unroll
    for (int s = 0; s < 2; s++) {
      const unsigned a0 = pk[4 * s + 0], a1 = pk[4 * s + 1];
      const unsigned a2 = pk[4 * s + 2], a3 = pk[4 * s + 3];
      const unsigned x0 = (unsigned)__shfl_xor((int)a0, 32);
      const unsigned x1 = (unsigned)__shfl_xor((int)a1, 32);
      const unsigned x2 = (unsigned)__shfl_xor((int)a2, 32);
      const unsigned x3 = (unsigned)__shfl_xor((int)a3, 32);
      union { int4 i; s16x8 v; } u;
      u.i.x = (int)(hi ? x2 : a0);
      u.i.y = (int)(hi ? x3 : a1);
      u.i.z = (int)(hi ? a2 : x0);
      u.i.w = (int)(hi ? a3 : x1);
      o0 = __builtin_amdgcn_mfma_f32_32x32x16_bf16(u.v, vf[2 * s + 0], o0, 0, 0, 0);
      o1 = __builtin_amdgcn_mfma_f32_32x32x16_bf16(u.v, vf[2 * s + 1], o1, 0, 0, 0);
    }
  }

  // Opart layout [ks][jt][h][j32][d64], ML [ks][jt][h][j32][2]
  float* ob = Opart + (((size_t)(ks * 64 + jt) * 16 + h) * 32) * 64;
#pragma unroll
  for (int r = 0; r < 16; r++) {
    const int jj = (r & 3) + 8 * (r >> 2) + 4 * hi;
    ob[(size_t)jj * 64 + ln] = o0[r];
    ob[(size_t)jj * 64 + 32 + ln] = o1[r];
  }
  if (hi == 0) {
    float* mlp = ML + (((size_t)(ks * 64 + jt) * 16 + h) * 32 + ln) * 2;
    mlp[0] = mrun;
    mlp[1] = lrun;
  }
}

// ---------------------------------------------------------------- combine k-splits -> attn_flat bf16 [2048][1024]
__global__ void k_combine(const float* __restrict__ Opart, const float* __restrict__ ML,
                          unsigned short* __restrict__ attn_flat) {
  const int j = blockIdx.x, t = threadIdx.x;
  const int jt = j >> 5, jl = j & 31;
  const int d = t >> 2;
  unsigned short tmp[4];
#pragma unroll
  for (int q = 0; q < 4; q++) {
    const int hh = 4 * (t & 3) + q;
    float m[4], lv[4];
#pragma unroll
    for (int ksi = 0; ksi < 4; ksi++) {
      const size_t base = ((size_t)(ksi * 64 + jt) * 16 + hh) * 32 + jl;
      m[ksi] = ML[base * 2];
      lv[ksi] = ML[base * 2 + 1];
    }
    const float M = fmaxf(fmaxf(m[0], m[1]), fmaxf(m[2], m[3]));
    float L = 0.f, acc = 0.f;
#pragma unroll
    for (int ksi = 0; ksi < 4; ksi++) {
      const float e = __expf(m[ksi] - M);
      L += lv[ksi] * e;
      const size_t base = ((size_t)(ksi * 64 + jt) * 16 + hh) * 32 + jl;
      acc += Opart[base * 64 + d] * e;
    }
    tmp[q] = f2bf(acc / L);
  }
  ushort4 outv;
  outv.x = tmp[0]; outv.y = tmp[1]; outv.z = tmp[2]; outv.w = tmp[3];
  *(ushort4*)(attn_flat + (size_t)j * 1024 + t * 4) = outv;
}

// ---------------------------------------------------------------- launch
extern "C" void kernel_launch(void* const* d_in, const int* in_sizes, int n_in,
                              void* d_out, int out_size, void* d_ws, size_t ws_size,
                              hipStream_t stream) {
  const float* x     = (const float*)d_in[0];
  const float* bias  = (const float*)d_in[1];
  const int*   mask  = (const int*)d_in[2];
  const float* w_qkv = (const float*)d_in[3];
  const float* b_qkv = (const float*)d_in[4];
  const float* w_out = (const float*)d_in[5];
  const float* b_out = (const float*)d_in[6];
  float* out = (float*)d_out;

  char* ws = (char*)d_ws;
  unsigned short* xb   = (unsigned short*)(ws);                      // 4 MB
  unsigned short* wqb  = (unsigned short*)(ws + ((size_t)4 << 20));  // 6 MB
  unsigned short* wob  = (unsigned short*)(ws + ((size_t)10 << 20)); // 2 MB
  float* cost          = (float*)(ws + ((size_t)12 << 20));
  float* sint          = (float*)(ws + ((size_t)12 << 20) + (256 << 10));
  float* qkv           = (float*)(ws + ((size_t)13 << 20));          // 24 MB
  unsigned short* qhp  = (unsigned short*)(ws + ((size_t)37 << 20)); // 4 MB
  unsigned short* khp  = (unsigned short*)(ws + ((size_t)41 << 20)); // 4 MB
  unsigned short* vtp  = (unsigned short*)(ws + ((size_t)45 << 20)); // 4 MB
  unsigned short* af   = (unsigned short*)(ws + ((size_t)49 << 20)); // 4 MB
  float* Opart         = (float*)(ws + ((size_t)53 << 20));          // 33.6 MB
  float* ML            = (float*)(ws + ((size_t)88 << 20));          // 1 MB
  unsigned short* bmG  = (unsigned short*)(ws + ((size_t)90 << 20)); // 128 MB

  k_cvt_bf16<<<dim3(512), dim3(256), 0, stream>>>(x, xb, 2048 * 1024 / 4);
  k_cvt_bf16<<<dim3(512), dim3(256), 0, stream>>>(w_qkv, wqb, 3072 * 1024 / 4);
  k_cvt_bf16<<<dim3(512), dim3(256), 0, stream>>>(w_out, wob, 1024 * 1024 / 4);
  k_rope_table<<<dim3(256), dim3(256), 0, stream>>>(cost, sint);
  k_prep<<<dim3(64, 64), dim3(256), 0, stream>>>(bias, mask, bmG);
  k_gemm_bt<<<dim3(16, 24), dim3(256), 0, stream>>>(xb, wqb, b_qkv, qkv, 2048, 3072, 1024);
  k_rope_relayout<<<dim3(2048), dim3(256), 0, stream>>>(qkv, cost, sint, qhp, khp, vtp);
  k_attn<<<dim3(4, 64, 4), dim3(256), 0, stream>>>(bmG, qhp, khp, vtp, Opart, ML);
  k_combine<<<dim3(2048), dim3(256), 0, stream>>>(Opart, ML, af);
  k_gemm_bt<<<dim3(16, 8), dim3(256), 0, stream>>>(af, wob, b_out, out, 2048, 1024, 1024);
}

// Round 5
// 413.570 us; speedup vs baseline: 1.0041x; 1.0041x over previous
//
#include <hip/hip_runtime.h>
#include <stdint.h>
#include <math.h>

using f32x4  = __attribute__((ext_vector_type(4)))  float;
using f32x16 = __attribute__((ext_vector_type(16))) float;
using s16x8  = __attribute__((ext_vector_type(8)))  short;

#define DI __device__ __forceinline__

DI unsigned short f2bf(float f) {
  unsigned u = __float_as_uint(f);
  u += 0x7FFFu + ((u >> 16) & 1u);
  return (unsigned short)(u >> 16);
}
DI float bf2f(unsigned short h) { return __uint_as_float((unsigned)h << 16); }

// ---------------------------------------------------------------- f32 -> bf16
__global__ void k_cvt_bf16(const float* __restrict__ in, unsigned short* __restrict__ out, int n4) {
  int i = blockIdx.x * blockDim.x + threadIdx.x;
  const int stride = gridDim.x * blockDim.x;
  for (; i < n4; i += stride) {
    float4 v = reinterpret_cast<const float4*>(in)[i];
    ushort4 o;
    o.x = f2bf(v.x); o.y = f2bf(v.y); o.z = f2bf(v.z); o.w = f2bf(v.w);
    reinterpret_cast<ushort4*>(out)[i] = o;
  }
}

// ---------------------------------------------------------------- rope tables (2048 x 32)
__global__ void k_rope_table(float* __restrict__ cost, float* __restrict__ sint) {
  const int idx = blockIdx.x * 256 + threadIdx.x;  // 65536
  const int s = idx >> 5, fi = idx & 31;
  const double invf = pow(10000.0, -(double)fi / 32.0);
  const float ang = (float)s * (float)invf;
  cost[idx] = (float)cos((double)ang);
  sint[idx] = (float)sin((double)ang);
}

// ---------------------------------------------------------------- bf16 GEMM  C[M][N] = A[M][K]*B[N][K]^T + bias
__global__ __launch_bounds__(256) void k_gemm_bt(
    const unsigned short* __restrict__ A, const unsigned short* __restrict__ B,
    const float* __restrict__ bias, float* __restrict__ C, int M, int N, int K) {
  __shared__ unsigned short As[128 * 32], Bs[128 * 32];
  const int tid = threadIdx.x, l = tid & 63, w = tid >> 6;
  const int wr = w >> 1, wc = w & 1;
  const int m0 = blockIdx.x * 128, n0 = blockIdx.y * 128;
  const int srow = tid >> 2, scol = (tid & 3) * 8;
  f32x4 acc[4][4] = {};
  for (int k0 = 0; k0 < K; k0 += 32) {
    s16x8 a0 = *(const s16x8*)(A + (size_t)(m0 + srow) * K + k0 + scol);
    s16x8 a1 = *(const s16x8*)(A + (size_t)(m0 + 64 + srow) * K + k0 + scol);
    s16x8 b0 = *(const s16x8*)(B + (size_t)(n0 + srow) * K + k0 + scol);
    s16x8 b1 = *(const s16x8*)(B + (size_t)(n0 + 64 + srow) * K + k0 + scol);
    __syncthreads();
    *(s16x8*)&As[srow * 32 + scol] = a0;
    *(s16x8*)&As[(64 + srow) * 32 + scol] = a1;
    *(s16x8*)&Bs[srow * 32 + scol] = b0;
    *(s16x8*)&Bs[(64 + srow) * 32 + scol] = b1;
    __syncthreads();
    s16x8 af[4], bf[4];
#pragma unroll
    for (int i = 0; i < 4; i++)
      af[i] = *(const s16x8*)&As[(wr * 64 + i * 16 + (l & 15)) * 32 + (l >> 4) * 8];
#pragma unroll
    for (int j = 0; j < 4; j++)
      bf[j] = *(const s16x8*)&Bs[(wc * 64 + j * 16 + (l & 15)) * 32 + (l >> 4) * 8];
#pragma unroll
    for (int i = 0; i < 4; i++)
#pragma unroll
      for (int j = 0; j < 4; j++)
        acc[i][j] = __builtin_amdgcn_mfma_f32_16x16x32_bf16(af[i], bf[j], acc[i][j], 0, 0, 0);
  }
#pragma unroll
  for (int i = 0; i < 4; i++) {
    const int row = m0 + wr * 64 + i * 16 + (l >> 4) * 4;
#pragma unroll
    for (int j = 0; j < 4; j++) {
      const int col = n0 + wc * 64 + j * 16 + (l & 15);
      const float bv = bias ? bias[col] : 0.f;
#pragma unroll
      for (int r = 0; r < 4; r++) C[(size_t)(row + r) * N + col] = acc[i][j][r] + bv;
    }
  }
}

// ---------------------------------------------------------------- RoPE + relayout
// rotate_half pairs heads h^8 (sign - for h<8); tables indexed by (s, d&31).
__global__ void k_rope_relayout(const float* __restrict__ qkv, const float* __restrict__ cost,
                                const float* __restrict__ sint,
                                unsigned short* __restrict__ qh, unsigned short* __restrict__ kh,
                                unsigned short* __restrict__ vt) {
  const int s = blockIdx.x, t = threadIdx.x;
  const float* row = qkv + (size_t)s * 3072;
  const int c = t * 4;
  const int d = c >> 4;
  const int hbase = c & 15;
  const float cv = cost[s * 32 + (d & 31)];
  const float sv = sint[s * 32 + (d & 31)];
  const float sgn = (hbase < 8) ? -1.f : 1.f;
  {
    float4 v = *(const float4*)(row + c);
    float4 v2 = *(const float4*)(row + (c ^ 8));
    const float* vp = (const float*)&v;
    const float* vp2 = (const float*)&v2;
#pragma unroll
    for (int i = 0; i < 4; i++) {
      float val = vp[i] * cv + sgn * vp2[i] * sv;
      qh[(size_t)(hbase + i) * (2048 * 64) + s * 64 + d] = f2bf(val);
    }
  }
  {
    float4 v = *(const float4*)(row + 1024 + c);
    float4 v2 = *(const float4*)(row + 1024 + (c ^ 8));
    const float* vp = (const float*)&v;
    const float* vp2 = (const float*)&v2;
#pragma unroll
    for (int i = 0; i < 4; i++) {
      float val = vp[i] * cv + sgn * vp2[i] * sv;
      kh[(size_t)(hbase + i) * (2048 * 64) + s * 64 + d] = f2bf(val);
    }
  }
  {
    float4 v = *(const float4*)(row + 2048 + c);
    const float* vp = (const float*)&v;
#pragma unroll
    for (int i = 0; i < 4; i++)
      vt[(size_t)(hbase + i) * (64 * 2048) + (size_t)d * 2048 + s] = f2bf(vp[i]);
  }
}

// ---------------------------------------------------------------- bias+mask pre-pass (no LDS, no barriers)
// in : bias fp32 [j][k][h16], mask int32 same
// out: bmG bf16 [h][ko=k/4][j][ki=k%4]
// lane l = (h = l&15, ko_sub = l>>4); wave covers 8 j x 16 k x 16 h.
// Gather: 64+64 independent dword loads (4x64B segments per instr, every line fully used).
// Write: each lane owns one 64B line (4x uint4 contiguous).
__global__ __launch_bounds__(256) void k_prep(const float* __restrict__ bias,
                                              const int* __restrict__ mask,
                                              unsigned short* __restrict__ bmG) {
  const int t = threadIdx.x, w = t >> 6, l = t & 63;
  const int h = l & 15, kol = l >> 4;
  const int jt = blockIdx.x, kt = blockIdx.y;  // grid (256, 32)
  const int j0 = jt * 8;
  const int ko = kt * 16 + w * 4 + kol;
  const int kbase = ko * 4;

  float bv[8][4];
  int mv[8][4];
  const size_t rowb = ((size_t)j0 * 2048 + kbase) * 16 + h;
#pragma unroll
  for (int jj = 0; jj < 8; jj++)
#pragma unroll
    for (int ki = 0; ki < 4; ki++) {
      const size_t off = rowb + (size_t)jj * 32768 + (size_t)ki * 16;
      bv[jj][ki] = bias[off];
      mv[jj][ki] = mask[off];
    }

  unsigned short* outp = bmG + (((size_t)h * 512 + ko) * 2048 + j0) * 4;
#pragma unroll
  for (int jp = 0; jp < 4; jp++) {
    uint4 o;
    unsigned* op = (unsigned*)&o;
#pragma unroll
    for (int e = 0; e < 4; e++) {
      const int jj = jp * 2 + (e >> 1);
      const int k0 = (e & 1) * 2;
      const unsigned s0 = f2bf(mv[jj][k0] ? bv[jj][k0] : -1.0e8f);
      const unsigned s1 = f2bf(mv[jj][k0 + 1] ? bv[jj][k0 + 1] : -1.0e8f);
      op[e] = s0 | (s1 << 16);
    }
    *(uint4*)(outp + jp * 8) = o;
  }
}

// ---------------------------------------------------------------- attention (barrier-free)
// grid (q4=4, jt=64, ks=4), 256 threads = 4 waves, 1 head/wave, 32 q-rows, 512 k per block
__global__ __launch_bounds__(256, 4) void k_attn(
    const unsigned short* __restrict__ bmG,
    const unsigned short* __restrict__ qh, const unsigned short* __restrict__ kh,
    const unsigned short* __restrict__ vt,
    float* __restrict__ Opart, float* __restrict__ ML) {
  const int tid = threadIdx.x, l = tid & 63, w = tid >> 6;
  const int hi = l >> 5, ln = l & 31;
  const int q4 = blockIdx.x, jt = blockIdx.y, ks = blockIdx.z;
  const int j0 = jt * 32, h = q4 * 4 + w, kstart = ks * 512;

  s16x8 qf[4];
  {
    const unsigned short* qb = qh + ((size_t)h * 2048 + (j0 + ln)) * 64 + 8 * hi;
#pragma unroll
    for (int ds = 0; ds < 4; ds++) qf[ds] = *(const s16x8*)(qb + ds * 16);
  }
  const unsigned short* kb = kh + ((size_t)h * 2048 + (kstart + ln)) * 64 + 8 * hi;
  const unsigned short* vb = vt + (size_t)h * 64 * 2048 + (size_t)ln * 2048 + kstart + 8 * hi;
  const uint2* bp = (const uint2*)bmG + ((size_t)h * 512 + (size_t)ks * 128 + hi) * 2048 + j0 + ln;
  // chunk c at iter it lives at bp + (it*8 + 2c)*2048

  f32x16 o0 = {}, o1 = {};
  float mrun = -3.0e38f, lrun = 0.f;

  uint2 bnx1[4], bnx2[4];
#pragma unroll
  for (int c = 0; c < 4; c++) bnx1[c] = bp[(size_t)(2 * c) * 2048];
#pragma unroll
  for (int c = 0; c < 4; c++) bnx2[c] = bp[(size_t)(8 + 2 * c) * 2048];

  for (int it = 0; it < 16; ++it) {
    uint2 bcur[4];
#pragma unroll
    for (int c = 0; c < 4; c++) bcur[c] = bnx1[c];
#pragma unroll
    for (int c = 0; c < 4; c++) bnx1[c] = bnx2[c];
    if (it + 2 < 16) {
#pragma unroll
      for (int c = 0; c < 4; c++) bnx2[c] = bp[(size_t)((it + 2) * 8 + 2 * c) * 2048];
    }
    s16x8 kf[4], vf[4];
    {
      const unsigned short* kp = kb + (size_t)it * (32 * 64);
#pragma unroll
      for (int ds = 0; ds < 4; ds++) kf[ds] = *(const s16x8*)(kp + ds * 16);
      const unsigned short* vp = vb + (size_t)it * 32;
      vf[0] = *(const s16x8*)(vp);
      vf[1] = *(const s16x8*)(vp + 32 * 2048);
      vf[2] = *(const s16x8*)(vp + 16);
      vf[3] = *(const s16x8*)(vp + 32 * 2048 + 16);
    }
    // S^T = K*Q^T : reg r -> kl=(r&3)+8*(r>>2)+4*hi, lane ln -> j
    f32x16 st = {};
#pragma unroll
    for (int ds = 0; ds < 4; ds++)
      st = __builtin_amdgcn_mfma_f32_32x32x16_bf16(kf[ds], qf[ds], st, 0, 0, 0);
    float p[16];
    float tmax = -3.0e38f;
#pragma unroll
    for (int r = 0; r < 16; r++) {
      const unsigned word = (r & 2) ? bcur[r >> 2].y : bcur[r >> 2].x;
      const unsigned short u = (r & 1) ? (unsigned short)(word >> 16) : (unsigned short)(word & 0xffffu);
      const float sv = st[r] * 0.125f + bf2f(u);
      p[r] = sv;
      tmax = fmaxf(tmax, sv);
    }
    tmax = fmaxf(tmax, __shfl_xor(tmax, 32));
    const float mnew = fmaxf(mrun, tmax);
    const float sc = __expf(mrun - mnew);
    float psum = 0.f;
#pragma unroll
    for (int r = 0; r < 16; r++) { p[r] = __expf(p[r] - mnew); psum += p[r]; }
    psum += __shfl_xor(psum, 32);
    lrun = lrun * sc + psum;
    mrun = mnew;
#pragma unroll
    for (int r = 0; r < 16; r++) {
      const int jj = (r & 3) + 8 * (r >> 2) + 4 * hi;
      const float s2 = __shfl(sc, jj);
      o0[r] *= s2;
      o1[r] *= s2;
    }
    unsigned pk[8];
#pragma unroll
    for (int q = 0; q < 8; q++)
      pk[q] = (unsigned)f2bf(p[2 * q]) | ((unsigned)f2bf(p[2 * q + 1]) << 16);
#pragma unroll
    for (int s = 0; s < 2; s++) {
      const unsigned a0 = pk[4 * s + 0], a1 = pk[4 * s + 1];
      const unsigned a2 = pk[4 * s + 2], a3 = pk[4 * s + 3];
      const unsigned x0 = (unsigned)__shfl_xor((int)a0, 32);
      const unsigned x1 = (unsigned)__shfl_xor((int)a1, 32);
      const unsigned x2 = (unsigned)__shfl_xor((int)a2, 32);
      const unsigned x3 = (unsigned)__shfl_xor((int)a3, 32);
      union { int4 i; s16x8 v; } u;
      u.i.x = (int)(hi ? x2 : a0);
      u.i.y = (int)(hi ? x3 : a1);
      u.i.z = (int)(hi ? a2 : x0);
      u.i.w = (int)(hi ? a3 : x1);
      o0 = __builtin_amdgcn_mfma_f32_32x32x16_bf16(u.v, vf[2 * s + 0], o0, 0, 0, 0);
      o1 = __builtin_amdgcn_mfma_f32_32x32x16_bf16(u.v, vf[2 * s + 1], o1, 0, 0, 0);
    }
  }

  // Opart layout [ks][jt][h][j32][d64], ML [ks][jt][h][j32][2]
  float* ob = Opart + (((size_t)(ks * 64 + jt) * 16 + h) * 32) * 64;
#pragma unroll
  for (int r = 0; r < 16; r++) {
    const int jj = (r & 3) + 8 * (r >> 2) + 4 * hi;
    ob[(size_t)jj * 64 + ln] = o0[r];
    ob[(size_t)jj * 64 + 32 + ln] = o1[r];
  }
  if (hi == 0) {
    float* mlp = ML + (((size_t)(ks * 64 + jt) * 16 + h) * 32 + ln) * 2;
    mlp[0] = mrun;
    mlp[1] = lrun;
  }
}

// ---------------------------------------------------------------- combine k-splits -> attn_flat bf16 [2048][1024]
__global__ void k_combine(const float* __restrict__ Opart, const float* __restrict__ ML,
                          unsigned short* __restrict__ attn_flat) {
  const int j = blockIdx.x, t = threadIdx.x;
  const int jt = j >> 5, jl = j & 31;
  const int d = t >> 2;
  unsigned short tmp[4];
#pragma unroll
  for (int q = 0; q < 4; q++) {
    const int hh = 4 * (t & 3) + q;
    float m[4], lv[4];
#pragma unroll
    for (int ksi = 0; ksi < 4; ksi++) {
      const size_t base = ((size_t)(ksi * 64 + jt) * 16 + hh) * 32 + jl;
      m[ksi] = ML[base * 2];
      lv[ksi] = ML[base * 2 + 1];
    }
    const float M = fmaxf(fmaxf(m[0], m[1]), fmaxf(m[2], m[3]));
    float L = 0.f, acc = 0.f;
#pragma unroll
    for (int ksi = 0; ksi < 4; ksi++) {
      const float e = __expf(m[ksi] - M);
      L += lv[ksi] * e;
      const size_t base = ((size_t)(ksi * 64 + jt) * 16 + hh) * 32 + jl;
      acc += Opart[base * 64 + d] * e;
    }
    tmp[q] = f2bf(acc / L);
  }
  ushort4 outv;
  outv.x = tmp[0]; outv.y = tmp[1]; outv.z = tmp[2]; outv.w = tmp[3];
  *(ushort4*)(attn_flat + (size_t)j * 1024 + t * 4) = outv;
}

// ---------------------------------------------------------------- launch
extern "C" void kernel_launch(void* const* d_in, const int* in_sizes, int n_in,
                              void* d_out, int out_size, void* d_ws, size_t ws_size,
                              hipStream_t stream) {
  const float* x     = (const float*)d_in[0];
  const float* bias  = (const float*)d_in[1];
  const int*   mask  = (const int*)d_in[2];
  const float* w_qkv = (const float*)d_in[3];
  const float* b_qkv = (const float*)d_in[4];
  const float* w_out = (const float*)d_in[5];
  const float* b_out = (const float*)d_in[6];
  float* out = (float*)d_out;

  char* ws = (char*)d_ws;
  unsigned short* xb   = (unsigned short*)(ws);                      // 4 MB
  unsigned short* wqb  = (unsigned short*)(ws + ((size_t)4 << 20));  // 6 MB
  unsigned short* wob  = (unsigned short*)(ws + ((size_t)10 << 20)); // 2 MB
  float* cost          = (float*)(ws + ((size_t)12 << 20));
  float* sint          = (float*)(ws + ((size_t)12 << 20) + (256 << 10));
  float* qkv           = (float*)(ws + ((size_t)13 << 20));          // 24 MB
  unsigned short* qhp  = (unsigned short*)(ws + ((size_t)37 << 20)); // 4 MB
  unsigned short* khp  = (unsigned short*)(ws + ((size_t)41 << 20)); // 4 MB
  unsigned short* vtp  = (unsigned short*)(ws + ((size_t)45 << 20)); // 4 MB
  unsigned short* af   = (unsigned short*)(ws + ((size_t)49 << 20)); // 4 MB
  float* Opart         = (float*)(ws + ((size_t)53 << 20));          // 33.6 MB
  float* ML            = (float*)(ws + ((size_t)88 << 20));          // 1 MB
  unsigned short* bmG  = (unsigned short*)(ws + ((size_t)90 << 20)); // 128 MB

  k_cvt_bf16<<<dim3(512), dim3(256), 0, stream>>>(x, xb, 2048 * 1024 / 4);
  k_cvt_bf16<<<dim3(512), dim3(256), 0, stream>>>(w_qkv, wqb, 3072 * 1024 / 4);
  k_cvt_bf16<<<dim3(512), dim3(256), 0, stream>>>(w_out, wob, 1024 * 1024 / 4);
  k_rope_table<<<dim3(256), dim3(256), 0, stream>>>(cost, sint);
  k_prep<<<dim3(256, 32), dim3(256), 0, stream>>>(bias, mask, bmG);
  k_gemm_bt<<<dim3(16, 24), dim3(256), 0, stream>>>(xb, wqb, b_qkv, qkv, 2048, 3072, 1024);
  k_rope_relayout<<<dim3(2048), dim3(256), 0, stream>>>(qkv, cost, sint, qhp, khp, vtp);
  k_attn<<<dim3(4, 64, 4), dim3(256), 0, stream>>>(bmG, qhp, khp, vtp, Opart, ML);
  k_combine<<<dim3(2048), dim3(256), 0, stream>>>(Opart, ML, af);
  k_gemm_bt<<<dim3(16, 8), dim3(256), 0, stream>>>(af, wob, b_out, out, 2048, 1024, 1024);
}